// Round 3
// baseline (511.626 us; speedup 1.0000x reference)
//
#include <hip/hip_runtime.h>

#define IN_F 256
#define OUT_F 64
#define BKT_BITS 9           // 512 nodes per bucket
#define BKT_NODES 512
#define BKT_CAP 12288        // fixed bucket capacity; padded mean ~9984, sigma ~110 -> big margin
#define CHUNK 8192           // edges per block for binning pass
#define SRC_BITS 18          // N < 262144
#define SRC_MASK 0x3FFFF

typedef __attribute__((ext_vector_type(8))) short short8;    // 8 bf16 (4 VGPRs) — MFMA A/B frag
typedef __attribute__((ext_vector_type(4))) float floatx4;   // MFMA C/D frag

static __device__ __forceinline__ short f2bf_rne(float f) {
    unsigned u = __float_as_uint(f);
    unsigned r = (u + 0x7fffu + ((u >> 16) & 1u)) >> 16;  // round-nearest-even
    return (short)r;
}
static __device__ __forceinline__ float bf2f(short s) {
    return __uint_as_float(((unsigned)(unsigned short)s) << 16);
}

// ---------------- utility ----------------
__global__ void zero_kernel(int* __restrict__ p, int n) {
    int i = blockIdx.x * blockDim.x + threadIdx.x;
    if (i < n) p[i] = 0;
}

// ---------------- CSR build, pass 1: bin into fixed-capacity dst-buckets ----------------
// Block-local LDS hist -> one global atomic reservation per (block,bucket) ->
// contiguous ~42-edge runs per region (write amp ~1.2x, all from ONE block/XCD so the
// bucket window merges in that XCD's L2 — direct global scatter loses 8x here, R1 lesson).
// binned[bkt*BKT_CAP + i].x = (dst_offset_in_bucket << SRC_BITS) | src, .y = w bits.
__global__ __launch_bounds__(256) void bin_kernel(const int* __restrict__ src,
                                                  const int* __restrict__ dst,
                                                  const float* __restrict__ w,
                                                  int* __restrict__ bkt_cnt,
                                                  int2* __restrict__ binned, int E, int nbkt) {
    __shared__ int h[256];
    int t = threadIdx.x;
    h[t] = 0;
    __syncthreads();
    int base = blockIdx.x * CHUNK;
#pragma unroll
    for (int j = 0; j < CHUNK / 256; ++j) {
        int e = base + j * 256 + t;
        if (e < E) atomicAdd(&h[__builtin_nontemporal_load(dst + e) >> BKT_BITS], 1);
    }
    __syncthreads();
    int c = h[t];
    int rbase = 0;
    if (t < nbkt && c) rbase = atomicAdd(&bkt_cnt[t], c);
    __syncthreads();
    h[t] = rbase;  // becomes block-local cursor (offset within bucket region)
    __syncthreads();
#pragma unroll
    for (int j = 0; j < CHUNK / 256; ++j) {
        int e = base + j * 256 + t;
        if (e < E) {
            int d = dst[e];
            int bb = d >> BKT_BITS;
            int pos = atomicAdd(&h[bb], 1);
            binned[(size_t)bb * BKT_CAP + pos] =
                make_int2(((d & (BKT_NODES - 1)) << SRC_BITS) | src[e], __float_as_int(w[e]));
        }
    }
}

// ---------------- CSR build, pass 2 (fused): per-bucket count + padded scan + place + pad --
// Each node's slot count rounded up to a multiple of 8 (pads = src 0, w 0) so spmm has no
// remainder loop. Bucket base is the static b*BKT_CAP (no cross-bucket scan kernel needed);
// begs/ends are per-node explicit.
__global__ __launch_bounds__(256) void build_bucket_kernel(const int2* __restrict__ binned,
                                                           const int* __restrict__ bkt_cnt,
                                                           int* __restrict__ begs,
                                                           int* __restrict__ ends,
                                                           int2* __restrict__ edges,
                                                           int N) {
    __shared__ int h[BKT_NODES];   // per-node counts, then cursors
    __shared__ int ssum[256];
    int t = threadIdx.x;
    int b = blockIdx.x;
    h[t] = 0;
    h[t + 256] = 0;
    __syncthreads();
    int cntb = bkt_cnt[b];
    const int2* bsrc = binned + (size_t)b * BKT_CAP;
    for (int e = t; e < cntb; e += 256) atomicAdd(&h[bsrc[e].x >> SRC_BITS], 1);
    __syncthreads();
    // padded counts; exclusive scan of 512: thread t owns elements 2t, 2t+1
    int c0 = h[2 * t], c1 = h[2 * t + 1];
    int p0 = (c0 + 7) & ~7;
    int p1 = (c1 + 7) & ~7;
    ssum[t] = p0 + p1;
    __syncthreads();
    for (int off = 1; off < 256; off <<= 1) {
        int v = (t >= off) ? ssum[t - off] : 0;
        __syncthreads();
        ssum[t] += v;
        __syncthreads();
    }
    int base = b * BKT_CAP + (t > 0 ? ssum[t - 1] : 0);
    int node0 = (b << BKT_BITS) + 2 * t;
    if (node0 < N)     { begs[node0] = base;          ends[node0] = base + p0; }
    if (node0 + 1 < N) { begs[node0 + 1] = base + p0; ends[node0 + 1] = base + p0 + p1; }
    __syncthreads();  // all reads of h-as-counts done
    h[2 * t] = base;
    h[2 * t + 1] = base + p0;
    __syncthreads();
    for (int e = t; e < cntb; e += 256) {
        int2 v = bsrc[e];
        int pos = atomicAdd(&h[v.x >> SRC_BITS], 1);
        edges[pos] = make_int2(v.x & SRC_MASK, v.y);
    }
    __syncthreads();  // cursors final: base + exact count
    for (int k = h[2 * t]; k < base + p0; ++k) edges[k] = make_int2(0, 0);
    for (int k = h[2 * t + 1]; k < base + p0 + p1; ++k) edges[k] = make_int2(0, 0);
}

// ---------------- sort each node's edge list by src (locality-only; wave rank-sort) ------
// Concurrent waves then sweep src-space in the same order -> momentary gather working set
// ~few MB -> L2-resident. deg > 64 skips (correctness unaffected). Pads (src=0) sort front.
__global__ __launch_bounds__(256) void sort_kernel(const int* __restrict__ begs,
                                                   const int* __restrict__ ends,
                                                   int2* __restrict__ edges, int N) {
    int gid = blockIdx.x * blockDim.x + threadIdx.x;
    int node = __builtin_amdgcn_readfirstlane(gid >> 6);
    int lane = threadIdx.x & 63;
    if (node >= N) return;
    int beg = begs[node];
    int deg = ends[node] - beg;
    if (deg <= 8 || deg > 64) return;   // <=8: one batch, order irrelevant
    long long* ep = (long long*)edges;
    long long my = (lane < deg) ? ep[beg + lane] : 0;
    int mysrc = (int)my;                // low 32 bits = src
    int rank = 0;
    for (int k = 0; k < 64; ++k) {
        int sk = __shfl(mysrc, k);
        if (lane < deg && k < deg)
            rank += (sk < mysrc || (sk == mysrc && k < lane)) ? 1 : 0;
    }
    // wave-internal: all lanes' loads completed (waitcnt on `my`) before any store issues
    if (lane < deg) ep[beg + rank] = my;
}

// ---------------- W -> bf16 hi/lo MFMA B-fragments ----------------
__global__ void wfrag_kernel(const float* __restrict__ W,
                             short* __restrict__ bh, short* __restrict__ bl) {
    int t = blockIdx.x * blockDim.x + threadIdx.x;
    if (t >= 32 * 64) return;
    int combo = t >> 6;
    int lane = t & 63;
    int s = combo >> 2;
    int tO = combo & 3;
    int n = 16 * tO + (lane & 15);
    int k0 = 32 * s + (lane >> 4) * 8;
    const float* src = W + (size_t)n * IN_F + k0;
    short* dh = bh + (size_t)t * 8;
    short* dl = bl + (size_t)t * 8;
#pragma unroll
    for (int j = 0; j < 8; ++j) {
        float v = src[j];
        short h = f2bf_rne(v);
        dh[j] = h;
        dl[j] = f2bf_rne(v - bf2f(h));
    }
}

// ---------------- GEMM via MFMA bf16x3 ----------------
__global__ __launch_bounds__(256) void gemm_kernel(const float* __restrict__ x,
                                                   const short8* __restrict__ bh,
                                                   const short8* __restrict__ bl,
                                                   const float* __restrict__ b,
                                                   float* __restrict__ out, int N) {
    int lane = threadIdx.x & 63;
    int wid = threadIdx.x >> 6;
    int node0 = blockIdx.x * 64 + wid * 16;
    if (node0 >= N) return;
    if (node0 + 16 > N) node0 = N - 16;
    int m = lane & 15;
    int q = lane >> 4;

    // x is a pure 102MB stream with zero reuse: nontemporal keeps L2 for everything else
    const floatx4* xr = (const floatx4*)(x + (size_t)(node0 + m) * IN_F) + q * 2;

    floatx4 acc[4];
#pragma unroll
    for (int tO = 0; tO < 4; ++tO) acc[tO] = (floatx4){0.f, 0.f, 0.f, 0.f};

#pragma unroll
    for (int s = 0; s < 8; ++s) {
        floatx4 v0 = __builtin_nontemporal_load(xr + s * 8);
        floatx4 v1 = __builtin_nontemporal_load(xr + s * 8 + 1);
        float vv[8] = {v0[0], v0[1], v0[2], v0[3], v1[0], v1[1], v1[2], v1[3]};
        short8 ah, al;
#pragma unroll
        for (int j = 0; j < 8; ++j) {
            short h = f2bf_rne(vv[j]);
            ah[j] = h;
            al[j] = f2bf_rne(vv[j] - bf2f(h));
        }
#pragma unroll
        for (int tO = 0; tO < 4; ++tO) {
            short8 wh = bh[(s * 4 + tO) * 64 + lane];
            short8 wl = bl[(s * 4 + tO) * 64 + lane];
            acc[tO] = __builtin_amdgcn_mfma_f32_16x16x32_bf16(ah, wh, acc[tO], 0, 0, 0);
            acc[tO] = __builtin_amdgcn_mfma_f32_16x16x32_bf16(al, wh, acc[tO], 0, 0, 0);
            acc[tO] = __builtin_amdgcn_mfma_f32_16x16x32_bf16(ah, wl, acc[tO], 0, 0, 0);
        }
    }

#pragma unroll
    for (int tO = 0; tO < 4; ++tO) {
        float bias = b[16 * tO + m];
#pragma unroll
        for (int r = 0; r < 4; ++r) {
            out[(size_t)(node0 + q * 4 + r) * OUT_F + 16 * tO + m] = acc[tO][r] + bias;
        }
    }
}

// ---------------- SpMM (CSR gather): out[n][f] = sum_e w[e]*in[src[e]][f] ----------------
// Lists padded to multiples of 8 -> no remainder; 2-deep edge-batch pipeline; src-sorted
// lists -> coherent src sweep across concurrent waves. Edge stream + out store nontemporal.
__global__ __launch_bounds__(256) void spmm_kernel(const int* __restrict__ begs,
                                                   const int* __restrict__ ends,
                                                   const int2* __restrict__ edges,
                                                   const float* __restrict__ in,
                                                   float* __restrict__ out, int N) {
    int gid = blockIdx.x * blockDim.x + threadIdx.x;
    int node = __builtin_amdgcn_readfirstlane(gid >> 6);
    int lane = threadIdx.x & 63;
    if (node >= N) return;
    int e = begs[node];
    int end = ends[node];
    const long long* ep = (const long long*)edges;
    float acc = 0.f;
    if (e < end) {
        long long L[8];
#pragma unroll
        for (int j = 0; j < 8; ++j) L[j] = __builtin_nontemporal_load(ep + e + j);
        for (;;) {
            float v[8];
#pragma unroll
            for (int j = 0; j < 8; ++j) v[j] = in[(size_t)(int)L[j] * OUT_F + lane];
            int en = e + 8;
            long long Ln[8];
            if (en < end) {
#pragma unroll
                for (int j = 0; j < 8; ++j) Ln[j] = __builtin_nontemporal_load(ep + en + j);
            }
#pragma unroll
            for (int j = 0; j < 8; ++j) acc = fmaf(__int_as_float((int)(L[j] >> 32)), v[j], acc);
            if (en >= end) break;
#pragma unroll
            for (int j = 0; j < 8; ++j) L[j] = Ln[j];
            e = en;
        }
    }
    __builtin_nontemporal_store(acc, out + (size_t)node * OUT_F + lane);
}

// ---------------- launch ----------------
extern "C" void kernel_launch(void* const* d_in, const int* in_sizes, int n_in,
                              void* d_out, int out_size, void* d_ws, size_t ws_size,
                              hipStream_t stream) {
    const float* x = (const float*)d_in[0];
    const float* W = (const float*)d_in[1];
    const float* b = (const float*)d_in[2];
    const int* esrc = (const int*)d_in[3];
    const int* edst = (const int*)d_in[4];
    const float* ew = (const float*)d_in[5];
    float* out = (float*)d_out;

    int N = in_sizes[0] / IN_F;
    int E = in_sizes[3];
    int nbkt = (N + BKT_NODES - 1) >> BKT_BITS;   // 196 for N=100000 (must be <= 256)

    char* ws = (char*)d_ws;
    size_t off = 0;
    float* buf0 = (float*)(ws + off);    off += (size_t)N * OUT_F * sizeof(float);
    int2* edges = (int2*)(ws + off);     off += (size_t)nbkt * BKT_CAP * sizeof(int2);
    int* begs = (int*)(ws + off);        off += (size_t)N * sizeof(int);
    int* ends = (int*)(ws + off);        off += (size_t)N * sizeof(int);
    int* bkt_cnt = (int*)(ws + off);     off += 1024 * sizeof(int);
    short* bh = (short*)(ws + off);      off += 32 * 64 * 8 * sizeof(short);
    short* bl = (short*)(ws + off);      off += 32 * 64 * 8 * sizeof(short);
    // binned aliases buf0's region (196*12288*8B = 19.3MB <= 25.6MB): buf0 is only
    // written by gemm, which runs after build_bucket_kernel consumed binned.
    int2* binned = (int2*)buf0;
    (void)ws_size; (void)n_in; (void)out_size;

    int nb_chunk = (E + CHUNK - 1) / CHUNK;

    // CSR build: 3 kernels (+ one-time locality sort)
    zero_kernel<<<1, 256, 0, stream>>>(bkt_cnt, nbkt);
    bin_kernel<<<nb_chunk, 256, 0, stream>>>(esrc, edst, ew, bkt_cnt, binned, E, nbkt);
    build_bucket_kernel<<<nbkt, 256, 0, stream>>>(binned, bkt_cnt, begs, ends, edges, N);
    sort_kernel<<<(N * 64 + 255) / 256, 256, 0, stream>>>(begs, ends, edges, N);

    // projection
    wfrag_kernel<<<8, 256, 0, stream>>>(W, bh, bl);
    gemm_kernel<<<(N + 63) / 64, 256, 0, stream>>>(x, (const short8*)bh, (const short8*)bl,
                                                   b, buf0, N);

    // 3 hops
    int spmm_blocks = (N * 64 + 255) / 256;
    spmm_kernel<<<spmm_blocks, 256, 0, stream>>>(begs, ends, edges, buf0, out, N);
    spmm_kernel<<<spmm_blocks, 256, 0, stream>>>(begs, ends, edges, out, buf0, N);
    spmm_kernel<<<spmm_blocks, 256, 0, stream>>>(begs, ends, edges, buf0, out, N);
}

// Round 4
// 424.102 us; speedup vs baseline: 1.2064x; 1.2064x over previous
//
#include <hip/hip_runtime.h>

#define IN_F 256
#define OUT_F 64
#define BKT_BITS 9           // 512 nodes per bucket
#define BKT_NODES 512
#define BKT_CAP 12288        // fixed bucket capacity; padded mean ~9984, sigma ~110 -> big margin
#define CHUNK 8192           // edges per block for binning pass
#define SRC_BITS 18          // N < 262144
#define SRC_MASK 0x3FFFF

typedef __attribute__((ext_vector_type(8))) short short8;    // 8 bf16 (4 VGPRs) — MFMA A/B frag
typedef __attribute__((ext_vector_type(4))) float floatx4;   // MFMA C/D frag

static __device__ __forceinline__ short f2bf_rne(float f) {
    unsigned u = __float_as_uint(f);
    unsigned r = (u + 0x7fffu + ((u >> 16) & 1u)) >> 16;  // round-nearest-even
    return (short)r;
}
static __device__ __forceinline__ float bf2f(short s) {
    return __uint_as_float(((unsigned)(unsigned short)s) << 16);
}

// ---------------- utility ----------------
__global__ void zero_kernel(int* __restrict__ p, int n) {
    int i = blockIdx.x * blockDim.x + threadIdx.x;
    if (i < n) p[i] = 0;
}

// ---------------- CSR build, pass 1: bin into fixed-capacity dst-buckets ----------------
// Block-local LDS hist -> one global atomic reservation per (block,bucket) ->
// contiguous ~42-edge runs per region (write amp ~1.2x, all from ONE block/XCD so the
// bucket window merges in that XCD's L2 — direct global scatter loses 8x here, R1 lesson).
// binned[bkt*BKT_CAP + i].x = (dst_offset_in_bucket << SRC_BITS) | src, .y = w bits.
__global__ __launch_bounds__(256) void bin_kernel(const int* __restrict__ src,
                                                  const int* __restrict__ dst,
                                                  const float* __restrict__ w,
                                                  int* __restrict__ bkt_cnt,
                                                  int2* __restrict__ binned, int E, int nbkt) {
    __shared__ int h[256];
    int t = threadIdx.x;
    h[t] = 0;
    __syncthreads();
    int base = blockIdx.x * CHUNK;
#pragma unroll
    for (int j = 0; j < CHUNK / 256; ++j) {
        int e = base + j * 256 + t;
        if (e < E) atomicAdd(&h[__builtin_nontemporal_load(dst + e) >> BKT_BITS], 1);
    }
    __syncthreads();
    int c = h[t];
    int rbase = 0;
    if (t < nbkt && c) rbase = atomicAdd(&bkt_cnt[t], c);
    __syncthreads();
    h[t] = rbase;  // becomes block-local cursor (offset within bucket region)
    __syncthreads();
#pragma unroll
    for (int j = 0; j < CHUNK / 256; ++j) {
        int e = base + j * 256 + t;
        if (e < E) {
            int d = dst[e];
            int bb = d >> BKT_BITS;
            int pos = atomicAdd(&h[bb], 1);
            binned[(size_t)bb * BKT_CAP + pos] =
                make_int2(((d & (BKT_NODES - 1)) << SRC_BITS) | src[e], __float_as_int(w[e]));
        }
    }
}

// ---------------- CSR build, pass 2 (fused): per-bucket count + padded scan + place + pad --
// Each node's slot count rounded up to a multiple of 8 (pads = src 0, w 0) so spmm has no
// remainder loop (remainder after 16-batches is exactly 0 or 8). Bucket base is the static
// b*BKT_CAP; begs/ends per-node explicit.
__global__ __launch_bounds__(256) void build_bucket_kernel(const int2* __restrict__ binned,
                                                           const int* __restrict__ bkt_cnt,
                                                           int* __restrict__ begs,
                                                           int* __restrict__ ends,
                                                           int2* __restrict__ edges,
                                                           int N) {
    __shared__ int h[BKT_NODES];   // per-node counts, then cursors
    __shared__ int ssum[256];
    int t = threadIdx.x;
    int b = blockIdx.x;
    h[t] = 0;
    h[t + 256] = 0;
    __syncthreads();
    int cntb = bkt_cnt[b];
    const int2* bsrc = binned + (size_t)b * BKT_CAP;
    for (int e = t; e < cntb; e += 256) atomicAdd(&h[bsrc[e].x >> SRC_BITS], 1);
    __syncthreads();
    // padded counts; exclusive scan of 512: thread t owns elements 2t, 2t+1
    int c0 = h[2 * t], c1 = h[2 * t + 1];
    int p0 = (c0 + 7) & ~7;
    int p1 = (c1 + 7) & ~7;
    ssum[t] = p0 + p1;
    __syncthreads();
    for (int off = 1; off < 256; off <<= 1) {
        int v = (t >= off) ? ssum[t - off] : 0;
        __syncthreads();
        ssum[t] += v;
        __syncthreads();
    }
    int base = b * BKT_CAP + (t > 0 ? ssum[t - 1] : 0);
    int node0 = (b << BKT_BITS) + 2 * t;
    if (node0 < N)     { begs[node0] = base;          ends[node0] = base + p0; }
    if (node0 + 1 < N) { begs[node0 + 1] = base + p0; ends[node0 + 1] = base + p0 + p1; }
    __syncthreads();  // all reads of h-as-counts done
    h[2 * t] = base;
    h[2 * t + 1] = base + p0;
    __syncthreads();
    for (int e = t; e < cntb; e += 256) {
        int2 v = bsrc[e];
        int pos = atomicAdd(&h[v.x >> SRC_BITS], 1);
        edges[pos] = make_int2(v.x & SRC_MASK, v.y);
    }
    __syncthreads();  // cursors final: base + exact count
    for (int k = h[2 * t]; k < base + p0; ++k) edges[k] = make_int2(0, 0);
    for (int k = h[2 * t + 1]; k < base + p0 + p1; ++k) edges[k] = make_int2(0, 0);
}

// ---------------- W -> bf16 hi/lo MFMA B-fragments ----------------
__global__ void wfrag_kernel(const float* __restrict__ W,
                             short* __restrict__ bh, short* __restrict__ bl) {
    int t = blockIdx.x * blockDim.x + threadIdx.x;
    if (t >= 32 * 64) return;
    int combo = t >> 6;
    int lane = t & 63;
    int s = combo >> 2;
    int tO = combo & 3;
    int n = 16 * tO + (lane & 15);
    int k0 = 32 * s + (lane >> 4) * 8;
    const float* src = W + (size_t)n * IN_F + k0;
    short* dh = bh + (size_t)t * 8;
    short* dl = bl + (size_t)t * 8;
#pragma unroll
    for (int j = 0; j < 8; ++j) {
        float v = src[j];
        short h = f2bf_rne(v);
        dh[j] = h;
        dl[j] = f2bf_rne(v - bf2f(h));
    }
}

// ---------------- GEMM via MFMA bf16x3 ----------------
__global__ __launch_bounds__(256) void gemm_kernel(const float* __restrict__ x,
                                                   const short8* __restrict__ bh,
                                                   const short8* __restrict__ bl,
                                                   const float* __restrict__ b,
                                                   float* __restrict__ out, int N) {
    int lane = threadIdx.x & 63;
    int wid = threadIdx.x >> 6;
    int node0 = blockIdx.x * 64 + wid * 16;
    if (node0 >= N) return;
    if (node0 + 16 > N) node0 = N - 16;
    int m = lane & 15;
    int q = lane >> 4;

    // x is a pure 102MB stream with zero reuse: nontemporal keeps L2 for everything else
    const floatx4* xr = (const floatx4*)(x + (size_t)(node0 + m) * IN_F) + q * 2;

    floatx4 acc[4];
#pragma unroll
    for (int tO = 0; tO < 4; ++tO) acc[tO] = (floatx4){0.f, 0.f, 0.f, 0.f};

#pragma unroll
    for (int s = 0; s < 8; ++s) {
        floatx4 v0 = __builtin_nontemporal_load(xr + s * 8);
        floatx4 v1 = __builtin_nontemporal_load(xr + s * 8 + 1);
        float vv[8] = {v0[0], v0[1], v0[2], v0[3], v1[0], v1[1], v1[2], v1[3]};
        short8 ah, al;
#pragma unroll
        for (int j = 0; j < 8; ++j) {
            short h = f2bf_rne(vv[j]);
            ah[j] = h;
            al[j] = f2bf_rne(vv[j] - bf2f(h));
        }
#pragma unroll
        for (int tO = 0; tO < 4; ++tO) {
            short8 wh = bh[(s * 4 + tO) * 64 + lane];
            short8 wl = bl[(s * 4 + tO) * 64 + lane];
            acc[tO] = __builtin_amdgcn_mfma_f32_16x16x32_bf16(ah, wh, acc[tO], 0, 0, 0);
            acc[tO] = __builtin_amdgcn_mfma_f32_16x16x32_bf16(al, wh, acc[tO], 0, 0, 0);
            acc[tO] = __builtin_amdgcn_mfma_f32_16x16x32_bf16(ah, wl, acc[tO], 0, 0, 0);
        }
    }

#pragma unroll
    for (int tO = 0; tO < 4; ++tO) {
        float bias = b[16 * tO + m];
#pragma unroll
        for (int r = 0; r < 4; ++r) {
            out[(size_t)(node0 + q * 4 + r) * OUT_F + 16 * tO + m] = acc[tO][r] + bias;
        }
    }
}

// ---------------- SpMM (CSR gather): out[n][f] = sum_e w[e]*in[src[e]][f] ----------------
// Lists padded to multiples of 8 -> 16-deep gather batches (MLP=16), remainder exactly 0
// or 8. Edge stream + out store nontemporal; in-rows get all L2 capacity.
__global__ __launch_bounds__(256) void spmm_kernel(const int* __restrict__ begs,
                                                   const int* __restrict__ ends,
                                                   const int2* __restrict__ edges,
                                                   const float* __restrict__ in,
                                                   float* __restrict__ out, int N) {
    int gid = blockIdx.x * blockDim.x + threadIdx.x;
    int node = __builtin_amdgcn_readfirstlane(gid >> 6);
    int lane = threadIdx.x & 63;
    if (node >= N) return;
    int e = begs[node];
    int end = ends[node];
    const long long* ep = (const long long*)edges;
    float acc = 0.f;
    while (e + 16 <= end) {
        long long L[16];
        float v[16];
#pragma unroll
        for (int j = 0; j < 16; ++j) L[j] = __builtin_nontemporal_load(ep + e + j);
#pragma unroll
        for (int j = 0; j < 16; ++j) v[j] = in[(size_t)(int)L[j] * OUT_F + lane];
#pragma unroll
        for (int j = 0; j < 16; ++j) acc = fmaf(__int_as_float((int)(L[j] >> 32)), v[j], acc);
        e += 16;
    }
    if (e < end) {   // exactly 8 remain (lists padded to multiple of 8)
        long long L[8];
        float v[8];
#pragma unroll
        for (int j = 0; j < 8; ++j) L[j] = __builtin_nontemporal_load(ep + e + j);
#pragma unroll
        for (int j = 0; j < 8; ++j) v[j] = in[(size_t)(int)L[j] * OUT_F + lane];
#pragma unroll
        for (int j = 0; j < 8; ++j) acc = fmaf(__int_as_float((int)(L[j] >> 32)), v[j], acc);
    }
    __builtin_nontemporal_store(acc, out + (size_t)node * OUT_F + lane);
}

// ---------------- launch ----------------
extern "C" void kernel_launch(void* const* d_in, const int* in_sizes, int n_in,
                              void* d_out, int out_size, void* d_ws, size_t ws_size,
                              hipStream_t stream) {
    const float* x = (const float*)d_in[0];
    const float* W = (const float*)d_in[1];
    const float* b = (const float*)d_in[2];
    const int* esrc = (const int*)d_in[3];
    const int* edst = (const int*)d_in[4];
    const float* ew = (const float*)d_in[5];
    float* out = (float*)d_out;

    int N = in_sizes[0] / IN_F;
    int E = in_sizes[3];
    int nbkt = (N + BKT_NODES - 1) >> BKT_BITS;   // 196 for N=100000 (must be <= 256)

    char* ws = (char*)d_ws;
    size_t off = 0;
    float* buf0 = (float*)(ws + off);    off += (size_t)N * OUT_F * sizeof(float);
    int2* edges = (int2*)(ws + off);     off += (size_t)nbkt * BKT_CAP * sizeof(int2);
    int* begs = (int*)(ws + off);        off += (size_t)N * sizeof(int);
    int* ends = (int*)(ws + off);        off += (size_t)N * sizeof(int);
    int* bkt_cnt = (int*)(ws + off);     off += 1024 * sizeof(int);
    short* bh = (short*)(ws + off);      off += 32 * 64 * 8 * sizeof(short);
    short* bl = (short*)(ws + off);      off += 32 * 64 * 8 * sizeof(short);
    // binned aliases buf0's region (196*12288*8B = 19.3MB <= 25.6MB): buf0 is only
    // written by gemm, which runs after build_bucket_kernel consumed binned.
    int2* binned = (int2*)buf0;
    (void)ws_size; (void)n_in; (void)out_size;

    int nb_chunk = (E + CHUNK - 1) / CHUNK;

    // CSR build: 3 kernels
    zero_kernel<<<1, 256, 0, stream>>>(bkt_cnt, nbkt);
    bin_kernel<<<nb_chunk, 256, 0, stream>>>(esrc, edst, ew, bkt_cnt, binned, E, nbkt);
    build_bucket_kernel<<<nbkt, 256, 0, stream>>>(binned, bkt_cnt, begs, ends, edges, N);

    // projection
    wfrag_kernel<<<8, 256, 0, stream>>>(W, bh, bl);
    gemm_kernel<<<(N + 63) / 64, 256, 0, stream>>>(x, (const short8*)bh, (const short8*)bl,
                                                   b, buf0, N);

    // 3 hops
    int spmm_blocks = (N * 64 + 255) / 256;
    spmm_kernel<<<spmm_blocks, 256, 0, stream>>>(begs, ends, edges, buf0, out, N);
    spmm_kernel<<<spmm_blocks, 256, 0, stream>>>(begs, ends, edges, out, buf0, N);
    spmm_kernel<<<spmm_blocks, 256, 0, stream>>>(begs, ends, edges, buf0, out, N);
}

// Round 6
// 419.477 us; speedup vs baseline: 1.2197x; 1.0110x over previous
//
#include <hip/hip_runtime.h>

#define IN_F 256
#define OUT_F 64
#define BKT_BITS 8           // 256 nodes per bucket
#define BKT_NODES 256
#define BKT_CAP 6656         // mean cnt 4096 (sigma 64) + pad mean ~900 -> +20 sigma margin
#define CHUNK 2048           // edges per block for binning pass (782 blocks -> full CU fill)
#define SRC_BITS 18          // N < 262144
#define SRC_MASK 0x3FFFF

typedef __attribute__((ext_vector_type(8))) short short8;    // 8 bf16 (4 VGPRs) — MFMA A/B frag
typedef __attribute__((ext_vector_type(4))) float floatx4;   // MFMA C/D frag
typedef __attribute__((ext_vector_type(4))) int intx4;       // 2 edges per 16B load

static __device__ __forceinline__ short f2bf_rne(float f) {
    unsigned u = __float_as_uint(f);
    unsigned r = (u + 0x7fffu + ((u >> 16) & 1u)) >> 16;  // round-nearest-even
    return (short)r;
}
static __device__ __forceinline__ float bf2f(short s) {
    return __uint_as_float(((unsigned)(unsigned short)s) << 16);
}

// ---------------- utility ----------------
__global__ void zero_kernel(int* __restrict__ p, int n) {
    int i = blockIdx.x * blockDim.x + threadIdx.x;
    if (i < n) p[i] = 0;
}

// ---------------- CSR build, pass 1: bin into fixed-capacity dst-buckets ----------------
// Block-local LDS hist -> one global atomic reservation per (block,bucket) -> short
// contiguous runs per region, all from ONE block/XCD so the bucket window merges in that
// XCD's L2 (direct global scatter loses 8x here, R1 lesson).
// binned[bkt*BKT_CAP + i].x = (dst_offset_in_bucket << SRC_BITS) | src, .y = w bits.
__global__ __launch_bounds__(256) void bin_kernel(const int* __restrict__ src,
                                                  const int* __restrict__ dst,
                                                  const float* __restrict__ w,
                                                  int* __restrict__ bkt_cnt,
                                                  int2* __restrict__ binned, int E, int nbkt) {
    __shared__ int h[512];           // nbkt = 391 <= 512
    int t = threadIdx.x;
    h[t] = 0;
    h[t + 256] = 0;
    __syncthreads();
    int base = blockIdx.x * CHUNK;
#pragma unroll
    for (int j = 0; j < CHUNK / 256; ++j) {
        int e = base + j * 256 + t;
        if (e < E) atomicAdd(&h[__builtin_nontemporal_load(dst + e) >> BKT_BITS], 1);
    }
    __syncthreads();
    int c0 = h[t], c1 = h[t + 256];
    int r0 = 0, r1 = 0;
    if (t < nbkt && c0) r0 = atomicAdd(&bkt_cnt[t], c0);
    if (t + 256 < nbkt && c1) r1 = atomicAdd(&bkt_cnt[t + 256], c1);
    __syncthreads();
    h[t] = r0;       // becomes block-local cursor (offset within bucket region)
    h[t + 256] = r1;
    __syncthreads();
#pragma unroll
    for (int j = 0; j < CHUNK / 256; ++j) {
        int e = base + j * 256 + t;
        if (e < E) {
            int d = dst[e];
            int bb = d >> BKT_BITS;
            int pos = atomicAdd(&h[bb], 1);
            binned[(size_t)bb * BKT_CAP + pos] =
                make_int2(((d & (BKT_NODES - 1)) << SRC_BITS) | src[e], __float_as_int(w[e]));
        }
    }
}

// ---------------- CSR build, pass 2 (fused): per-bucket count + padded scan + place + pad --
// Node slot counts rounded up to a multiple of 8 (pads = src 0, w 0) so spmm has no
// remainder. Bucket base is the static b*BKT_CAP; per-node (beg,end) packed in one int2
// so spmm fetches both with a single s_load_dwordx2.
__global__ __launch_bounds__(256) void build_bucket_kernel(const int2* __restrict__ binned,
                                                           const int* __restrict__ bkt_cnt,
                                                           int2* __restrict__ bego,
                                                           int2* __restrict__ edges,
                                                           int N) {
    __shared__ int h[BKT_NODES];   // per-node counts, then cursors
    __shared__ int ssum[256];
    int t = threadIdx.x;
    int b = blockIdx.x;
    h[t] = 0;
    __syncthreads();
    int cntb = bkt_cnt[b];
    const int2* bsrc = binned + (size_t)b * BKT_CAP;
    for (int e = t; e < cntb; e += 256) atomicAdd(&h[bsrc[e].x >> SRC_BITS], 1);
    __syncthreads();
    int c = h[t];
    int p = (c + 7) & ~7;          // padded slot count
    ssum[t] = p;
    __syncthreads();
    for (int off = 1; off < 256; off <<= 1) {
        int v = (t >= off) ? ssum[t - off] : 0;
        __syncthreads();
        ssum[t] += v;
        __syncthreads();
    }
    int base = b * BKT_CAP + (t > 0 ? ssum[t - 1] : 0);
    int node = (b << BKT_BITS) + t;
    if (node < N) bego[node] = make_int2(base, base + p);
    __syncthreads();  // all reads of h-as-counts done
    h[t] = base;
    __syncthreads();
    for (int e = t; e < cntb; e += 256) {
        int2 v = bsrc[e];
        int pos = atomicAdd(&h[v.x >> SRC_BITS], 1);
        edges[pos] = make_int2(v.x & SRC_MASK, v.y);
    }
    __syncthreads();  // cursors final: base + exact count
    for (int k = h[t]; k < base + p; ++k) edges[k] = make_int2(0, 0);
}

// ---------------- W -> bf16 hi/lo MFMA B-fragments ----------------
__global__ void wfrag_kernel(const float* __restrict__ W,
                             short* __restrict__ bh, short* __restrict__ bl) {
    int t = blockIdx.x * blockDim.x + threadIdx.x;
    if (t >= 32 * 64) return;
    int combo = t >> 6;
    int lane = t & 63;
    int s = combo >> 2;
    int tO = combo & 3;
    int n = 16 * tO + (lane & 15);
    int k0 = 32 * s + (lane >> 4) * 8;
    const float* src = W + (size_t)n * IN_F + k0;
    short* dh = bh + (size_t)t * 8;
    short* dl = bl + (size_t)t * 8;
#pragma unroll
    for (int j = 0; j < 8; ++j) {
        float v = src[j];
        short h = f2bf_rne(v);
        dh[j] = h;
        dl[j] = f2bf_rne(v - bf2f(h));
    }
}

// ---------------- GEMM via MFMA bf16x3 ----------------
__global__ __launch_bounds__(256) void gemm_kernel(const float* __restrict__ x,
                                                   const short8* __restrict__ bh,
                                                   const short8* __restrict__ bl,
                                                   const float* __restrict__ b,
                                                   float* __restrict__ out, int N) {
    int lane = threadIdx.x & 63;
    int wid = threadIdx.x >> 6;
    int node0 = blockIdx.x * 64 + wid * 16;
    if (node0 >= N) return;
    if (node0 + 16 > N) node0 = N - 16;
    int m = lane & 15;
    int q = lane >> 4;

    // x is a pure 102MB stream with zero reuse: nontemporal keeps L2 for everything else
    const floatx4* xr = (const floatx4*)(x + (size_t)(node0 + m) * IN_F) + q * 2;

    floatx4 acc[4];
#pragma unroll
    for (int tO = 0; tO < 4; ++tO) acc[tO] = (floatx4){0.f, 0.f, 0.f, 0.f};

#pragma unroll
    for (int s = 0; s < 8; ++s) {
        floatx4 v0 = __builtin_nontemporal_load(xr + s * 8);
        floatx4 v1 = __builtin_nontemporal_load(xr + s * 8 + 1);
        float vv[8] = {v0[0], v0[1], v0[2], v0[3], v1[0], v1[1], v1[2], v1[3]};
        short8 ah, al;
#pragma unroll
        for (int j = 0; j < 8; ++j) {
            short h = f2bf_rne(vv[j]);
            ah[j] = h;
            al[j] = f2bf_rne(vv[j] - bf2f(h));
        }
#pragma unroll
        for (int tO = 0; tO < 4; ++tO) {
            short8 wh = bh[(s * 4 + tO) * 64 + lane];
            short8 wl = bl[(s * 4 + tO) * 64 + lane];
            acc[tO] = __builtin_amdgcn_mfma_f32_16x16x32_bf16(ah, wh, acc[tO], 0, 0, 0);
            acc[tO] = __builtin_amdgcn_mfma_f32_16x16x32_bf16(al, wh, acc[tO], 0, 0, 0);
            acc[tO] = __builtin_amdgcn_mfma_f32_16x16x32_bf16(ah, wl, acc[tO], 0, 0, 0);
        }
    }

#pragma unroll
    for (int tO = 0; tO < 4; ++tO) {
        float bias = b[16 * tO + m];
#pragma unroll
        for (int r = 0; r < 4; ++r) {
            out[(size_t)(node0 + q * 4 + r) * OUT_F + 16 * tO + m] = acc[tO][r] + bias;
        }
    }
}

// ---------------- SpMM (CSR gather): out[n][f] = sum_e w[e]*in[src[e]][f] ----------------
// Padded deg distribution: {8: 2%, 16: 53%, 24: 43%, >=32: 1.5%}. Single-shot gather paths
// for 8/16/24 (all gathers in flight, zero inter-batch drain); generic 16-loop otherwise.
// Edge loads as intx4 (2 edges / 16B instr; lists 64B-aligned by construction).
// NB = number of intx4 quads = deg/2.
#define GATHER_Q(NB)                                                                     \
    {                                                                                    \
        intx4 Q[NB];                                                                     \
        float v[2 * NB];                                                                 \
        _Pragma("unroll") for (int j = 0; j < NB; ++j)                                   \
            Q[j] = __builtin_nontemporal_load(eq + j);                                   \
        _Pragma("unroll") for (int j = 0; j < NB; ++j) {                                 \
            v[2 * j]     = in[(size_t)Q[j][0] * OUT_F + lane];                           \
            v[2 * j + 1] = in[(size_t)Q[j][2] * OUT_F + lane];                           \
        }                                                                                \
        _Pragma("unroll") for (int j = 0; j < NB; ++j) {                                 \
            acc = fmaf(__int_as_float(Q[j][1]), v[2 * j], acc);                          \
            acc = fmaf(__int_as_float(Q[j][3]), v[2 * j + 1], acc);                      \
        }                                                                                \
    }

__global__ __launch_bounds__(256) void spmm_kernel(const int2* __restrict__ bego,
                                                   const int2* __restrict__ edges,
                                                   const float* __restrict__ in,
                                                   float* __restrict__ out, int N) {
    int gid = blockIdx.x * blockDim.x + threadIdx.x;
    int node = __builtin_amdgcn_readfirstlane(gid >> 6);
    int lane = threadIdx.x & 63;
    if (node >= N) return;
    int2 be = bego[node];            // wave-uniform -> one s_load_dwordx2
    int e = be.x;
    int end = be.y;
    int deg = end - e;
    float acc = 0.f;
    const intx4* eq = (const intx4*)(edges + e);
    if (deg == 16) {
        GATHER_Q(8)
    } else if (deg == 24) {
        GATHER_Q(12)
    } else if (deg == 8) {
        GATHER_Q(4)
    } else {
        while (e + 16 <= end) {
            GATHER_Q(8)
            e += 16;
            eq = (const intx4*)(edges + e);
        }
        if (e < end) {   // exactly 8 remain (padded to multiple of 8)
            GATHER_Q(4)
        }
    }
    __builtin_nontemporal_store(acc, out + (size_t)node * OUT_F + lane);
}

// ---------------- launch ----------------
extern "C" void kernel_launch(void* const* d_in, const int* in_sizes, int n_in,
                              void* d_out, int out_size, void* d_ws, size_t ws_size,
                              hipStream_t stream) {
    const float* x = (const float*)d_in[0];
    const float* W = (const float*)d_in[1];
    const float* b = (const float*)d_in[2];
    const int* esrc = (const int*)d_in[3];
    const int* edst = (const int*)d_in[4];
    const float* ew = (const float*)d_in[5];
    float* out = (float*)d_out;

    int N = in_sizes[0] / IN_F;
    int E = in_sizes[3];
    int nbkt = (N + BKT_NODES - 1) >> BKT_BITS;   // 391 for N=100000 (must be <= 512)

    char* ws = (char*)d_ws;
    size_t off = 0;
    float* buf0 = (float*)(ws + off);    off += (size_t)N * OUT_F * sizeof(float);
    int2* edges = (int2*)(ws + off);     off += (size_t)nbkt * BKT_CAP * sizeof(int2);
    int2* bego = (int2*)(ws + off);      off += (size_t)N * sizeof(int2);
    int* bkt_cnt = (int*)(ws + off);     off += 1024 * sizeof(int);
    short* bh = (short*)(ws + off);      off += 32 * 64 * 8 * sizeof(short);
    short* bl = (short*)(ws + off);      off += 32 * 64 * 8 * sizeof(short);
    // binned aliases buf0's region (391*6656*8B = 20.8MB <= 25.6MB): buf0 is only
    // written by gemm, which runs after build_bucket_kernel consumed binned.
    int2* binned = (int2*)buf0;
    (void)ws_size; (void)n_in; (void)out_size;

    int nb_chunk = (E + CHUNK - 1) / CHUNK;   // 782 blocks

    // CSR build: 3 kernels
    zero_kernel<<<2, 256, 0, stream>>>(bkt_cnt, nbkt);
    bin_kernel<<<nb_chunk, 256, 0, stream>>>(esrc, edst, ew, bkt_cnt, binned, E, nbkt);
    build_bucket_kernel<<<nbkt, 256, 0, stream>>>(binned, bkt_cnt, bego, edges, N);

    // projection
    wfrag_kernel<<<8, 256, 0, stream>>>(W, bh, bl);
    gemm_kernel<<<(N + 63) / 64, 256, 0, stream>>>(x, (const short8*)bh, (const short8*)bl,
                                                   b, buf0, N);

    // 3 hops
    int spmm_blocks = (N * 64 + 255) / 256;
    spmm_kernel<<<spmm_blocks, 256, 0, stream>>>(bego, edges, buf0, out, N);
    spmm_kernel<<<spmm_blocks, 256, 0, stream>>>(bego, edges, out, buf0, N);
    spmm_kernel<<<spmm_blocks, 256, 0, stream>>>(bego, edges, buf0, out, N);
}